// Round 1
// 254.782 us; speedup vs baseline: 1.0406x; 1.0406x over previous
//
#include <hip/hip_runtime.h>
#include <math.h>

#define H  128
#define S  8
#define BB 8   // batches per block, one wave each (512-thread blocks)

__device__ __forceinline__ float wave_sum(float v) {
    #pragma unroll
    for (int off = 32; off; off >>= 1) v += __shfl_xor(v, off, 64);
    return v;
}

// Single fused kernel, half-wave slot layout:
//   gather: 4 x dwordx4 per lane covers all 8 slots (lanes 0-31 = even slot,
//   32-63 = odd slot of each pair). Reductions: 5-step butterfly within the
//   half-wave + one xor-32 to share across halves.
// Epilogue is a block-cooperative split-K GEMM: each wave owns a 16-row
// K-slice of attn_W (prefetched to registers at kernel start) and computes
// partials for ALL 8 batches; partials reduced through LDS. attn_W traffic:
// 640 KB/block -> 128 KB/block vs the per-wave full-matrix stream.
__global__ __launch_bounds__(512, 4) void fused_kernel(
        const float* __restrict__ memory,    // [R,S,H]
        const float* __restrict__ o_emb_w,   // [H]
        const float* __restrict__ o_emb_r,   // [B,H]
        const float* __restrict__ attn_W,    // [H,H]
        const float* __restrict__ sim_w,     // [2H]
        const float* __restrict__ sim_b,     // [1]
        const float* __restrict__ forget_w,  // [2H]
        const int*   __restrict__ o_rg_p,
        const int*   __restrict__ d_rg,      // [B]
        float* __restrict__ out) {           // [B,H]
    // part[] aliases the attention-phase storage (all dead by the time part
    // is written; barrier 3 enforces the WAR ordering). Static LDS = 64 KB.
    __shared__ union SM {
        struct { float v1s[H]; float v2s[H]; float wm[BB][H]; } a;
        float4 part[2 * BB][BB][H / 4];      // [K-slice][batch][col4]
    } sm;

    const int u  = threadIdx.x;
    const int wv = u >> 6;     // wave id == batch-within-block (0..7)
    const int L  = u & 63;
    const int c  = L & 31;     // float4 column index
    const int hi = L >> 5;     // 0 = even slots, 1 = odd slots
    const int b  = blockIdx.x * BB + wv;

    const int o_rg = o_rg_p[0];
    const int r    = d_rg[b];

    // ---- gather first (latency-heavy): 4 x 16B loads = whole 4 KB region ----
    const float4* src4 = (const float4*)(memory + (size_t)r * (S * H));
    float4 rows[4];
    #pragma unroll
    for (int j = 0; j < 4; ++j) rows[j] = src4[j * 64 + L];
    const float2 oe = ((const float2*)o_emb_r)[(size_t)b * (H / 2) + L];

    // ---- prefetch this wave's epilogue K-slice of attn_W: rows i0..i0+7,
    //      column group c. Latency hides under the v1/v2 barrier. ----
    const int i0 = wv * 16 + hi * 8;
    const float4* W4 = (const float4*)attn_W;
    float4 Wreg[8];
    #pragma unroll
    for (int k = 0; k < 8; ++k) Wreg[k] = W4[(i0 + k) * (H / 4) + c];

    // ---- v1 = attn_W @ sim_w[:H], v2 = attn_W @ sim_w[H:], fused single
    //      pass over attn_W (64 KB instead of 128 KB), threads 0..127 ----
    if (u < H) {
        const float4* wr = W4 + u * (H / 4);
        const float4* s1 = (const float4*)sim_w;
        const float4* s2 = (const float4*)(sim_w + H);
        float a1 = 0.f, a2 = 0.f;
        #pragma unroll 8
        for (int j = 0; j < 32; ++j) {
            float4 w = wr[j], x1 = s1[j], x2 = s2[j];
            a1 += w.x * x1.x + w.y * x1.y + w.z * x1.z + w.w * x1.w;
            a2 += w.x * x2.x + w.y * x2.y + w.z * x2.z + w.w * x2.w;
        }
        sm.a.v1s[u] = a1;
        sm.a.v2s[u] = a2;
    }
    __syncthreads();   // [1]

    // ---- rare: this wave's region is the written one -> forget-gate fix ----
    if (r == o_rg) {
        const float4 ow4 = ((const float4*)o_emb_w)[c];
        const float4 f24 = ((const float4*)(forget_w + H))[c];
        const float2 ow2 = ((const float2*)o_emb_w)[L];
        const float2 f12 = ((const float2*)forget_w)[L];
        const float base = wave_sum(ow2.x * f12.x + ow2.y * f12.y);
        #pragma unroll
        for (int j = 0; j < 4; ++j) {
            float v = rows[j].x * f24.x + rows[j].y * f24.y
                    + rows[j].z * f24.z + rows[j].w * f24.w;
            #pragma unroll
            for (int off = 1; off <= 16; off <<= 1) v += __shfl_xor(v, off, 64);
            float g = 1.f / (1.f + expf(-(base + v)));
            rows[j].x = rows[j].x * (1.f - g) + ow4.x * g;
            rows[j].y = rows[j].y * (1.f - g) + ow4.y * g;
            rows[j].z = rows[j].z * (1.f - g) + ow4.z * g;
            rows[j].w = rows[j].w * (1.f - g) + ow4.w * g;
        }
    }

    // ---- attention logits ----
    const float2 vv1 = ((const float2*)sm.a.v1s)[L];
    const float  qs  = wave_sum(oe.x * vv1.x + oe.y * vv1.y);
    const float4 vv2 = ((const float4*)sm.a.v2s)[c];

    float d2own[4], d2oth[4];   // own-half slot order; softmax is order-invariant
    #pragma unroll
    for (int j = 0; j < 4; ++j) {
        float v = rows[j].x * vv2.x + rows[j].y * vv2.y
                + rows[j].z * vv2.z + rows[j].w * vv2.w;
        #pragma unroll
        for (int off = 1; off <= 16; off <<= 1) v += __shfl_xor(v, off, 64);
        d2own[j] = v;
        d2oth[j] = __shfl_xor(v, 32, 64);
    }

    const float sb = sim_b[0];
    float lown[4], loth[4], m = -INFINITY;
    #pragma unroll
    for (int j = 0; j < 4; ++j) {
        lown[j] = fmaxf(qs + d2own[j] + sb, 0.f);
        loth[j] = fmaxf(qs + d2oth[j] + sb, 0.f);
        m = fmaxf(m, fmaxf(lown[j], loth[j]));
    }
    float pown[4], psum = 0.f;
    #pragma unroll
    for (int j = 0; j < 4; ++j) {
        pown[j] = expf(lown[j] - m);
        psum += pown[j] + expf(loth[j] - m);
    }
    const float inv = 1.f / psum;

    // weighted slot mix: own-half slots only, then combine halves
    float4 wm = {0.f, 0.f, 0.f, 0.f};
    #pragma unroll
    for (int j = 0; j < 4; ++j) {
        float ps = pown[j] * inv;
        wm.x += ps * rows[j].x;
        wm.y += ps * rows[j].y;
        wm.z += ps * rows[j].z;
        wm.w += ps * rows[j].w;
    }
    wm.x += __shfl_xor(wm.x, 32, 64);
    wm.y += __shfl_xor(wm.y, 32, 64);
    wm.z += __shfl_xor(wm.z, 32, 64);
    wm.w += __shfl_xor(wm.w, 32, 64);
    if (hi == 0) ((float4*)sm.a.wm[wv])[c] = wm;
    __syncthreads();   // [2] wm visible to all waves

    // ---- epilogue: split-K, each wave covers rows [i0, i0+8) of attn_W for
    //      ALL 8 batches; wm reads are half-wave broadcasts (free) ----
    float4 acc[BB];
    const int q0 = i0 >> 2;
    #pragma unroll
    for (int bb = 0; bb < BB; ++bb) {
        const float4 m0 = ((const float4*)sm.a.wm[bb])[q0];
        const float4 m1 = ((const float4*)sm.a.wm[bb])[q0 + 1];
        float4 a;
        a.x = m0.x * Wreg[0].x + m0.y * Wreg[1].x + m0.z * Wreg[2].x + m0.w * Wreg[3].x
            + m1.x * Wreg[4].x + m1.y * Wreg[5].x + m1.z * Wreg[6].x + m1.w * Wreg[7].x;
        a.y = m0.x * Wreg[0].y + m0.y * Wreg[1].y + m0.z * Wreg[2].y + m0.w * Wreg[3].y
            + m1.x * Wreg[4].y + m1.y * Wreg[5].y + m1.z * Wreg[6].y + m1.w * Wreg[7].y;
        a.z = m0.x * Wreg[0].z + m0.y * Wreg[1].z + m0.z * Wreg[2].z + m0.w * Wreg[3].z
            + m1.x * Wreg[4].z + m1.y * Wreg[5].z + m1.z * Wreg[6].z + m1.w * Wreg[7].z;
        a.w = m0.x * Wreg[0].w + m0.y * Wreg[1].w + m0.z * Wreg[2].w + m0.w * Wreg[3].w
            + m1.x * Wreg[4].w + m1.y * Wreg[5].w + m1.z * Wreg[6].w + m1.w * Wreg[7].w;
        acc[bb] = a;
    }
    __syncthreads();   // [3] all sm.a reads done before part overwrites the union

    #pragma unroll
    for (int bb = 0; bb < BB; ++bb) sm.part[wv * 2 + hi][bb][c] = acc[bb];
    __syncthreads();   // [4] partials visible

    // ---- final 16-way K-slice reduction + store, threads 0..255 ----
    if (u < 256) {
        const int bb = u >> 5, cc = u & 31;
        float4 s0 = sm.part[0][bb][cc];
        #pragma unroll
        for (int k = 1; k < 16; ++k) {
            const float4 p = sm.part[k][bb][cc];
            s0.x += p.x; s0.y += p.y; s0.z += p.z; s0.w += p.w;
        }
        ((float4*)out)[(size_t)(blockIdx.x * BB + bb) * (H / 4) + cc] = s0;
    }
}

extern "C" void kernel_launch(void* const* d_in, const int* in_sizes, int n_in,
                              void* d_out, int out_size, void* d_ws, size_t ws_size,
                              hipStream_t stream) {
    const float* memory   = (const float*)d_in[0];
    const float* o_emb_w  = (const float*)d_in[1];
    const float* o_emb_r  = (const float*)d_in[2];
    const float* attn_W   = (const float*)d_in[3];
    const float* sim_w    = (const float*)d_in[4];
    const float* sim_b    = (const float*)d_in[5];
    const float* forget_w = (const float*)d_in[6];
    const int*   o_rg     = (const int*)d_in[7];
    const int*   d_rg     = (const int*)d_in[8];
    float* out = (float*)d_out;

    const int B = in_sizes[8];  // 4096

    fused_kernel<<<B / BB, 512, 0, stream>>>(
        memory, o_emb_w, o_emb_r, attn_W, sim_w, sim_b, forget_w, o_rg, d_rg, out);
}